// Round 23
// baseline (50.617 us; speedup 1.0000x reference)
//
#include <hip/hip_runtime.h>
#include <hip/hip_bf16.h>
#include <hip/hip_fp16.h>
#include <math.h>

// B=8, N=16384 (H=W=128), C=64, heads=1, d=64, SR=8 -> Nk=256.
// S = X @ (Wq K^T)/8 ; P = softmax(S) ; out = P @ (V Wp) + bp
// Algebra (R10): WK2 = SC*(Wkv_K @ Wq^T), WV2 = Wkv_V @ Wp, u = SC*Wkv_K@bq,
// bp2 = bp + bkv_V@Wp.
// R23: attn LDS cut to EXACTLY 32768B -> 5 blocks/CU (was 35328B -> 4).
//  (a) sSB dropped; bias ushorts from global per kt (R20-proven pattern).
//  (b) epilogue sOut = 4x[32][64] fp32 unpadded; bank conflicts avoided by
//      XOR swizzle slot = col4 ^ (row&7) applied on both LDS write and read.
//  (c) single-chain kt body (R18's, 64 VGPR) since 5 waves/SIMD needs <=102;
//      R19's 2-way interleave (~110 VGPR) would cap occupancy at 4 anyway.
// DEAD (do not retry): rolling VpT reg-prefetch / full-unroll attn (R12,R16)
// and launch_bounds-forced 8 waves/SIMD (R21): scratch-spill fingerprint.

#define B 8
#define N 16384
#define C 64
#define NK 256
#define HW 128

typedef unsigned short ushort_t;
typedef unsigned int uint_t;
typedef __attribute__((ext_vector_type(8))) short short8v;
typedef __attribute__((ext_vector_type(16))) float f32x16;

static __device__ inline ushort_t f2bf(float f) {
  __hip_bfloat16 h = __float2bfloat16(f);
  return *reinterpret_cast<ushort_t*>(&h);
}
// single-instruction packed convert: dst.lo = bf16(a), dst.hi = bf16(b)
static __device__ inline uint_t cvtpk(float a, float b) {
  uint_t r;
  asm("v_cvt_pk_bf16_f32 %0, %1, %2" : "=v"(r) : "v"(a), "v"(b));
  return r;
}
// packed f32x2 -> f16x2 (v_cvt_pkrtz_f16_f32, single instruction)
static __device__ inline uint_t pkh(float a, float b) {
  auto h2 = __builtin_amdgcn_cvt_pkrtz(a, b);
  return *reinterpret_cast<uint_t*>(&h2);
}
static __device__ inline float uf16lo(uint_t v) {
  ushort_t s = (ushort_t)v;
  _Float16 h = *reinterpret_cast<_Float16*>(&s);
  return (float)h;
}
static __device__ inline float uf16hi(uint_t v) {
  ushort_t s = (ushort_t)(v >> 16);
  _Float16 h = *reinterpret_cast<_Float16*>(&s);
  return (float)h;
}
static __device__ inline short8v mk8(uint_t a, uint_t b, uint_t c, uint_t d) {
  union { int4 i; short8v s; } u;
  u.i = make_int4((int)a, (int)b, (int)c, (int)d);
  return u.s;
}
static __device__ inline float sum16(const f32x16 v) {
  float a = ((v[0] + v[1]) + (v[2] + v[3])) + ((v[4] + v[5]) + (v[6] + v[7]));
  float b = ((v[8] + v[9]) + (v[10] + v[11])) + ((v[12] + v[13]) + (v[14] + v[15]));
  return a + b;
}

// ---------------------------------------------------------------------------
// Kernel 1 (prep0): blocks [0,1024): sr_w -> Wf fragment layout.
// Blocks [1024,1040): WK2/WV2 (B-fragment-linear).  Block 1040: u, bp2.
__global__ __launch_bounds__(256) void prep0(
    const float* __restrict__ sr_w, const float* __restrict__ Wq,
    const float* __restrict__ Wkv, const float* __restrict__ bq,
    const float* __restrict__ Wp, const float* __restrict__ bkv,
    const float* __restrict__ bp, ushort_t* __restrict__ Wf,
    ushort_t* __restrict__ W2f, float* __restrict__ u,
    float* __restrict__ bp2) {
  const int bid = blockIdx.x;
  const int t = threadIdx.x;
  const float SC = 0.125f * 1.4426950408889634f;
  if (bid < 1024) {
    int idx = bid * 256 + t;      // 262144
    int o = idx >> 12;
    int r = idx & 4095;
    int c = r >> 6;
    int ki = (r >> 3) & 7;
    int kj = r & 7;
    int oh = o >> 5;
    int l = ((c >> 3) & 1) * 32 + (o & 31);
    int kk = kj * 4 + (c >> 4);
    int e = c & 7;
    Wf[(ki * 2 + oh) * 16384 + kk * 512 + l * 8 + e] = f2bf(sr_w[idx]);
  } else if (bid < 1040) {
    const int eb = bid - 1024;
#pragma unroll
    for (int q = 0; q < 2; ++q) {
      int oidx = eb * 512 + t * 2 + q;   // [0,8192)
      int mat = oidx >> 12;
      int rem = oidx & 4095;
      int d = rem >> 6;
      int c = rem & 63;
      float s = 0.f;
      if (mat == 0) {
        const float* wk = Wkv + d * 128;
        const float* wq = Wq + c * 64;
#pragma unroll 16
        for (int e = 0; e < 64; ++e) s += wk[e] * wq[e];
        s *= SC;
      } else {
        const float* wk = Wkv + d * 128 + 64;
#pragma unroll 16
        for (int e = 0; e < 64; ++e) s += wk[e] * Wp[e * 64 + c];
      }
      W2f[((mat * 2 + (c >> 5)) * 4 + (d >> 4)) * 512 +
          (((d >> 3) & 1) * 32 + (c & 31)) * 8 + (d & 7)] = f2bf(s);
    }
  } else {
    if (t < 64) {
      float s = 0.f;
      const float* wk = Wkv + t * 128;
#pragma unroll 16
      for (int e = 0; e < 64; ++e) s += wk[e] * bq[e];
      u[t] = s * SC;
    } else if (t < 128) {
      int c = t - 64;
      float s = bp[c];
#pragma unroll 16
      for (int e = 0; e < 64; ++e) s += bkv[64 + e] * Wp[e * 64 + c];
      bp2[c] = s;
    }
  }
}

// ---------------------------------------------------------------------------
// Kernel A: conv partial GEMM, K-split by kj-halves; fp16 partials (R18).
// Grid 1024 = half(2) x b(8) x pg(8) x ki(8). 128 thr = 2 waves (oh).
__global__ __launch_bounds__(128) void conv_mfma(
    const float* __restrict__ x, const ushort_t* __restrict__ Wf,
    ushort_t* __restrict__ parth) {
  const int t = threadIdx.x;
  const int bi = blockIdx.x;
  const int ki = bi & 7;
  const int pg = (bi >> 3) & 7;
  const int b = (bi >> 6) & 7;
  const int half = bi >> 9;
  const int oh = t >> 6;
  const int lane = t & 63;
  const int lo5 = lane & 31;
  const int hi = lane >> 5;

  const int P = pg * 32 + lo5;
  const int prow = P >> 4, pcol = P & 15;
  const float* rowbase =
      x + ((size_t)b * N + (prow * 8 + ki) * HW + pcol * 8) * C;
  const ushort_t* wbase = Wf + (ki * 2 + oh) * 16384 + lane * 8;

  f32x16 acc;
#pragma unroll
  for (int r = 0; r < 16; ++r) acc[r] = 0.f;

#pragma unroll
  for (int kkl = 0; kkl < 16; ++kkl) {
    const int kk = half * 16 + kkl;
    const int kj = kk >> 2;
    const int c0 = (kk & 3) * 16 + hi * 8;
    const float4* xp = reinterpret_cast<const float4*>(rowbase + kj * C + c0);
    float4 f0 = xp[0];
    float4 f1 = xp[1];
    short8v bfr = mk8(cvtpk(f0.x, f0.y), cvtpk(f0.z, f0.w), cvtpk(f1.x, f1.y),
                      cvtpk(f1.z, f1.w));
    short8v afr = *reinterpret_cast<const short8v*>(wbase + kk * 512);
    acc = __builtin_amdgcn_mfma_f32_32x32x16_bf16(afr, bfr, acc, 0, 0, 0);
  }

  // fp16 partials: 16 values -> 8 packed uints -> 2 coalesced 16B stores
  ushort_t* dst = parth + (size_t)bi * 2048 + oh * 1024 + lane * 16;
  uint4 v0 = make_uint4(pkh(acc[0], acc[1]), pkh(acc[2], acc[3]),
                        pkh(acc[4], acc[5]), pkh(acc[6], acc[7]));
  uint4 v1 = make_uint4(pkh(acc[8], acc[9]), pkh(acc[10], acc[11]),
                        pkh(acc[12], acc[13]), pkh(acc[14], acc[15]));
  *reinterpret_cast<uint4*>(dst) = v0;
  *reinterpret_cast<uint4*>(dst + 8) = v1;
}

// ---------------------------------------------------------------------------
// Kernel L: sum 16 K-split fp16 partials + bias + LayerNorm + MT/Vp/sb.
// Grid 64 = b(8) x pg(8).
__global__ __launch_bounds__(256) void ln_prep(
    const ushort_t* __restrict__ parth, const float* __restrict__ sr_b,
    const float* __restrict__ ln_g, const float* __restrict__ ln_b,
    const ushort_t* __restrict__ W2f, const float* __restrict__ u,
    ushort_t* __restrict__ MTf, ushort_t* __restrict__ VpTf,
    ushort_t* __restrict__ sbf) {
  __shared__ float convs[32 * 68];
  __shared__ float ns[32 * 68];

  const int t = threadIdx.x;
  const int b = blockIdx.x >> 3;
  const int pg = blockIdx.x & 7;
  const size_t obase = (size_t)b * 16384;

  // ---- Phase A: sum 16 (ki, half) fp16 partials + conv bias ----
  {
    const int lane = t & 63;
    const int rhalf = (t >> 6) & 1;
    const int oh = t >> 7;
    float a[8];
#pragma unroll
    for (int r = 0; r < 8; ++r) a[r] = 0.f;
#pragma unroll
    for (int k2 = 0; k2 < 16; ++k2) {
      int bi = (k2 & 7) + (pg << 3) + (b << 6) + ((k2 >> 3) << 9);
      const ushort_t* src =
          parth + (size_t)bi * 2048 + oh * 1024 + lane * 16 + rhalf * 8;
      uint4 uv = *reinterpret_cast<const uint4*>(src);
      a[0] += uf16lo(uv.x); a[1] += uf16hi(uv.x);
      a[2] += uf16lo(uv.y); a[3] += uf16hi(uv.y);
      a[4] += uf16lo(uv.z); a[5] += uf16hi(uv.z);
      a[6] += uf16lo(uv.w); a[7] += uf16hi(uv.w);
    }
    const int p = lane & 31;
#pragma unroll
    for (int r = 0; r < 8; ++r) {
      int reg = rhalf * 8 + r;
      int o = oh * 32 + (reg & 3) + 8 * (reg >> 2) + 4 * (lane >> 5);
      convs[p * 68 + o] = a[r] + sr_b[o];
    }
  }
  __syncthreads();
  // ---- Phase B: LayerNorm ----
  {
    const int lane = t & 63;
    const int w = t >> 6;
    float g = ln_g[lane], bb = ln_b[lane];
#pragma unroll
    for (int rr = 0; rr < 8; ++rr) {
      int p = w * 8 + rr;
      float v = convs[p * 68 + lane];
      float s = v, s2 = v * v;
#pragma unroll
      for (int mask = 1; mask < 64; mask <<= 1) {
        s += __shfl_xor(s, mask, 64);
        s2 += __shfl_xor(s2, mask, 64);
      }
      float mu = s * (1.f / 64.f);
      float var = s2 * (1.f / 64.f) - mu * mu;
      ns[p * 68 + lane] = (v - mu) * rsqrtf(var + 1e-5f) * g + bb;
    }
  }
  __syncthreads();
  // ---- Phase C: per-wave 32x32 GEMM tile (MT / Vp) + sb dot ----
  {
    const int w = t >> 6;
    const int lane = t & 63;
    const int lo5 = lane & 31;
    const int hi = lane >> 5;
    const int mat = w >> 1;
    const int n0 = w & 1;

    f32x16 acc;
#pragma unroll
    for (int r = 0; r < 16; ++r) acc[r] = 0.f;
#pragma unroll
    for (int ks = 0; ks < 4; ++ks) {
      float4 f0 = *reinterpret_cast<const float4*>(&ns[lo5 * 68 + ks * 16 + hi * 8]);
      float4 f1 = *reinterpret_cast<const float4*>(&ns[lo5 * 68 + ks * 16 + hi * 8 + 4]);
      short8v A = mk8(cvtpk(f0.x, f0.y), cvtpk(f0.z, f0.w), cvtpk(f1.x, f1.y),
                      cvtpk(f1.z, f1.w));
      short8v Bw = *reinterpret_cast<const short8v*>(
          W2f + ((mat * 2 + n0) * 4 + ks) * 512 + lane * 8);
      acc = __builtin_amdgcn_mfma_f32_32x32x16_bf16(A, Bw, acc, 0, 0, 0);
    }
    const int c = n0 * 32 + lo5;
    if (mat == 0) {
#pragma unroll
      for (int r = 0; r < 16; ++r) {
        int jl = (r & 3) + 8 * (r >> 2) + 4 * hi;
        MTf[obase + (pg * 4 + (c >> 4)) * 512 +
            (((c >> 3) & 1) * 32 + jl) * 8 + (c & 7)] = f2bf(acc[r]);
      }
    } else {
#pragma unroll
      for (int r = 0; r < 16; ++r) {
        int jg = pg * 32 + (r & 3) + 8 * (r >> 2) + 4 * hi;
        VpTf[obase + (n0 * 16 + (jg >> 4)) * 512 +
             (((jg >> 3) & 1) * 32 + (c & 31)) * 8 + (jg & 7)] = f2bf(acc[r]);
      }
    }
    if (w == 0) {
      float s = 0.f;
      const float* ub = u + hi * 32;
#pragma unroll 8
      for (int dd = 0; dd < 32; ++dd) s += ns[lo5 * 68 + hi * 32 + dd] * ub[dd];
      s += __shfl_xor(s, 32, 64);
      if (hi == 0) sbf[b * NK + pg * 32 + lo5] = f2bf(s);
    }
  }
}

// ---------------------------------------------------------------------------
// Kernel B (R23): fused attention, LDS = exactly 32768B (sMT only) ->
// 5 blocks/CU = 20 waves/CU. Single-chain kt body (64 VGPR). Bias from
// global (L2-hot). Epilogue overlays sMT as 4x[32][64] fp32 with XOR
// swizzle (slot = col4 ^ (row&7)) on both write and read.
// Grid 1024 = b(8 hi) x qb(128); 256 thr = 4 waves.
__global__ __launch_bounds__(256, 4) void attn_mfma(
    const float* __restrict__ x, const ushort_t* __restrict__ MTf,
    const ushort_t* __restrict__ VpTf, const ushort_t* __restrict__ sbf,
    const float* __restrict__ bp2, float* __restrict__ outp) {
  __shared__ __align__(16) char smem[32768];
  ushort_t* sMT = reinterpret_cast<ushort_t*>(smem);
  float* sOut = reinterpret_cast<float*>(smem);

  const int t = threadIdx.x;
  const int b = blockIdx.x >> 7;
  const int qb = blockIdx.x & 127;
  const int wave = t >> 6;
  const int lane = t & 63;
  const int lo5 = lane & 31;
  const int hi = lane >> 5;

  // ---- issue x loads FIRST (latency hides under staging + barrier) ----
  const int row = qb * 128 + wave * 32 + lo5;
  const float4* xp =
      reinterpret_cast<const float4*>(x + ((size_t)b * N + row) * 64);
  float4 xf[8];
#pragma unroll
  for (int ks = 0; ks < 4; ++ks) {
    xf[2 * ks + 0] = xp[ks * 4 + hi * 2 + 0];
    xf[2 * ks + 1] = xp[ks * 4 + hi * 2 + 1];
  }

  // ---- cooperative staging: MT (256 threads, 32KB) ----
  {
    const uint4* gm = reinterpret_cast<const uint4*>(MTf + (size_t)b * 16384);
    uint4* dm = reinterpret_cast<uint4*>(sMT);
#pragma unroll
    for (int i = 0; i < 8; ++i) dm[t + i * 256] = gm[t + i * 256];
  }
  __syncthreads();

  // ---- pack X B-fragment (col=q=lane&31, k=c=ks*16+hi*8+e) ----
  short8v bx[4];
#pragma unroll
  for (int ks = 0; ks < 4; ++ks) {
    bx[ks] = mk8(cvtpk(xf[2 * ks].x, xf[2 * ks].y),
                 cvtpk(xf[2 * ks].z, xf[2 * ks].w),
                 cvtpk(xf[2 * ks + 1].x, xf[2 * ks + 1].y),
                 cvtpk(xf[2 * ks + 1].z, xf[2 * ks + 1].w));
  }

  const ushort_t* vt = VpTf + (size_t)b * 16384 + lane * 8;
  const ushort_t* sbg = sbf + b * NK + lo5;

  f32x16 zv;
#pragma unroll
  for (int r = 0; r < 16; ++r) zv[r] = 0.f;

  f32x16 o[2];
#pragma unroll
  for (int ct = 0; ct < 2; ++ct)
#pragma unroll
    for (int r = 0; r < 16; ++r) o[ct][r] = 0.f;
  float sum = 0.f;

#pragma unroll 2
  for (int kt = 0; kt < 8; ++kt) {
    // bias ushort from global (L2-hot; consumed ~5 MFMAs later)
    ushort_t sv = sbg[kt * 32];
    // ---- QK^T for this 32-key tile (first MFMA consumes zero C) ----
    __builtin_amdgcn_s_setprio(1);
    const short8v af0 =
        *reinterpret_cast<const short8v*>(&sMT[(kt * 4 + 0) * 512 + lane * 8]);
    f32x16 a0 = __builtin_amdgcn_mfma_f32_32x32x16_bf16(af0, bx[0], zv, 0, 0, 0);
#pragma unroll
    for (int ks = 1; ks < 4; ++ks) {
      const short8v a =
          *reinterpret_cast<const short8v*>(&sMT[(kt * 4 + ks) * 512 + lane * 8]);
      a0 = __builtin_amdgcn_mfma_f32_32x32x16_bf16(a, bx[ks], a0, 0, 0, 0);
    }
    // bias k-step: adds sb[key] to every query column
    {
      short8v a5 = mk8(hi ? 0u : (uint_t)sv, 0u, 0u, 0u);
      short8v b5 = mk8(hi ? 0u : 0x3F80u, 0u, 0u, 0u);
      a0 = __builtin_amdgcn_mfma_f32_32x32x16_bf16(a5, b5, a0, 0, 0, 0);
    }
    __builtin_amdgcn_s_setprio(0);
    // ---- exp2: bare v_exp_f32 (logits |s|<~10) ----
#pragma unroll
    for (int r = 0; r < 16; ++r) a0[r] = __builtin_amdgcn_exp2f(a0[r]);
    sum += sum16(a0);
    // ---- pack P, accumulate PV (VpT fragments from global, L2-hot) ----
#pragma unroll
    for (int h = 0; h < 2; ++h) {
      const int m0 = 2 * h;
      uint_t Aw = cvtpk(a0[4 * m0 + 0], a0[4 * m0 + 1]);
      uint_t Bw = cvtpk(a0[4 * m0 + 2], a0[4 * m0 + 3]);
      uint_t Cw = cvtpk(a0[4 * m0 + 4], a0[4 * m0 + 5]);
      uint_t Dw = cvtpk(a0[4 * m0 + 6], a0[4 * m0 + 7]);
      asm volatile("v_permlane32_swap_b32 %0, %1" : "+v"(Aw), "+v"(Cw));
      asm volatile("v_permlane32_swap_b32 %0, %1" : "+v"(Bw), "+v"(Dw));
      const short8v pb = mk8(Aw, Bw, Cw, Dw);
      __builtin_amdgcn_s_setprio(1);
#pragma unroll
      for (int ct = 0; ct < 2; ++ct) {
        const short8v va = *reinterpret_cast<const short8v*>(
            vt + (ct * 16 + kt * 2 + h) * 512);
        o[ct] = __builtin_amdgcn_mfma_f32_32x32x16_bf16(va, pb, o[ct], 0, 0, 0);
      }
      __builtin_amdgcn_s_setprio(0);
    }
  }

  sum += __shfl_xor(sum, 32, 64);
  const float linv = 1.f / sum;

  // ---- epilogue: swizzled LDS stage, then coalesced stores ----
  __syncthreads();   // all waves done reading sMT; region becomes sOut
  {
    float* wout = sOut + wave * 2048;   // [32][64] fp32, XOR-swizzled cols
#pragma unroll
    for (int ct = 0; ct < 2; ++ct) {
#pragma unroll
      for (int g4 = 0; g4 < 4; ++g4) {
        int c0 = ct * 32 + g4 * 8 + hi * 4;
        int g = c0 >> 2;                       // true float4-group 0..15
        float4 bpv = *reinterpret_cast<const float4*>(bp2 + c0);
        float4 r;
        r.x = o[ct][4 * g4 + 0] * linv + bpv.x;
        r.y = o[ct][4 * g4 + 1] * linv + bpv.y;
        r.z = o[ct][4 * g4 + 2] * linv + bpv.z;
        r.w = o[ct][4 * g4 + 3] * linv + bpv.w;
        *reinterpret_cast<float4*>(
            &wout[lo5 * 64 + (g ^ (lo5 & 7)) * 4]) = r;
      }
    }
  }
  __syncthreads();
  {
    float* outBase = outp + (((size_t)b * N + qb * 128) * 64);
#pragma unroll
    for (int qi = 0; qi < 8; ++qi) {
      int rowl = qi * 16 + (t >> 4);          // block-local query row 0..127
      int j = t & 15;                          // true float4-group
      float4 v = *reinterpret_cast<const float4*>(
          &sOut[(rowl >> 5) * 2048 + (rowl & 31) * 64 +
                ((j ^ (rowl & 7)) * 4)]);
      // linear float idx qi*1024 + t*4: consecutive lanes -> contiguous 16B
      *reinterpret_cast<float4*>(outBase + qi * 1024 + t * 4) = v;
    }
  }
}

// ---------------------------------------------------------------------------
extern "C" void kernel_launch(void* const* d_in, const int* in_sizes, int n_in,
                              void* d_out, int out_size, void* d_ws,
                              size_t ws_size, hipStream_t stream) {
  const float* x    = (const float*)d_in[0];
  const float* Wq   = (const float*)d_in[3];
  const float* bq   = (const float*)d_in[4];
  const float* Wkv  = (const float*)d_in[5];
  const float* bkv  = (const float*)d_in[6];
  const float* sr_w = (const float*)d_in[7];
  const float* sr_b = (const float*)d_in[8];
  const float* ln_g = (const float*)d_in[9];
  const float* ln_b = (const float*)d_in[10];
  const float* Wp   = (const float*)d_in[11];
  const float* bp   = (const float*)d_in[12];
  float* outp = (float*)d_out;

  char* ws = (char*)d_ws;
  // [0, 512K)      Wf    bf16 conv weight fragments
  // [512K, 528K)   W2f   bf16 WK2/WV2 fragments
  // [528K, +256)   u     fp32[64];  [+256, +512) bp2 fp32[64]
  // [1M, 5M)       parth fp16 conv partials (1024 units x 4KB)
  // [9M, 9.25M)    MTf   [9.25M, 9.5M) VpTf   [9.5M, +4K) sbf
  ushort_t* Wf    = (ushort_t*)(ws);
  ushort_t* W2f   = (ushort_t*)(ws + (512 << 10));
  float*    u     = (float*)(ws + (528 << 10));
  float*    bp2   = (float*)(ws + (528 << 10) + 256);
  ushort_t* parth = (ushort_t*)(ws + (1024 << 10));
  ushort_t* MTf   = (ushort_t*)(ws + (9216 << 10));
  ushort_t* VpTf  = (ushort_t*)(ws + (9472 << 10));
  ushort_t* sbf   = (ushort_t*)(ws + (9728 << 10));

  prep0<<<1041, 256, 0, stream>>>(sr_w, Wq, Wkv, bq, Wp, bkv, bp, Wf, W2f, u, bp2);
  conv_mfma<<<1024, 128, 0, stream>>>(x, Wf, parth);
  ln_prep<<<64, 256, 0, stream>>>(parth, sr_b, ln_g, ln_b, W2f, u, MTf, VpTf, sbf);
  attn_mfma<<<1024, 256, 0, stream>>>(x, MTf, VpTf, sbf, bp2, outp);
}

// Round 24
// 49.409 us; speedup vs baseline: 1.0244x; 1.0244x over previous
//
#include <hip/hip_runtime.h>
#include <hip/hip_bf16.h>
#include <hip/hip_fp16.h>
#include <math.h>

// B=8, N=16384 (H=W=128), C=64, heads=1, d=64, SR=8 -> Nk=256.
// S = X @ (Wq K^T)/8 ; P = softmax(S) ; out = P @ (V Wp) + bp
// Algebra (R10): WK2 = SC*(Wkv_K @ Wq^T), WV2 = Wkv_V @ Wp, u = SC*Wkv_K@bq,
// bp2 = bp + bkv_V@Wp.
// R24 = R19/R22 verbatim (best measured: 49.49/49.51us, reproduced twice).
// FINAL STATE. Exploration summary (all reverted with PMC evidence):
//  - occupancy: 2/SIMD=43us attn (R8), 4/SIMD+2-way ILP=best (R19),
//    5 blocks/CU=50.6 (R23), forced 8/SIMD=VGPR32 spill 94us (R21).
//  - prefetch/unroll (R12,R16): scratch-spill fingerprint (WRITE 148-167MB).
//  - VpT LDS staging/ping-pong (R9,R20): neutral; L2 already sufficient.
// Ceiling: attn ~28us vs ~13us overlapped-memory floor; per-kt dep-chain
// latency unpipelinable at HIP level within VGPR occupancy boundaries.

#define B 8
#define N 16384
#define C 64
#define NK 256
#define HW 128

typedef unsigned short ushort_t;
typedef unsigned int uint_t;
typedef __attribute__((ext_vector_type(8))) short short8v;
typedef __attribute__((ext_vector_type(16))) float f32x16;

static __device__ inline ushort_t f2bf(float f) {
  __hip_bfloat16 h = __float2bfloat16(f);
  return *reinterpret_cast<ushort_t*>(&h);
}
// single-instruction packed convert: dst.lo = bf16(a), dst.hi = bf16(b)
static __device__ inline uint_t cvtpk(float a, float b) {
  uint_t r;
  asm("v_cvt_pk_bf16_f32 %0, %1, %2" : "=v"(r) : "v"(a), "v"(b));
  return r;
}
// packed f32x2 -> f16x2 (v_cvt_pkrtz_f16_f32, single instruction)
static __device__ inline uint_t pkh(float a, float b) {
  auto h2 = __builtin_amdgcn_cvt_pkrtz(a, b);
  return *reinterpret_cast<uint_t*>(&h2);
}
static __device__ inline float uf16lo(uint_t v) {
  ushort_t s = (ushort_t)v;
  _Float16 h = *reinterpret_cast<_Float16*>(&s);
  return (float)h;
}
static __device__ inline float uf16hi(uint_t v) {
  ushort_t s = (ushort_t)(v >> 16);
  _Float16 h = *reinterpret_cast<_Float16*>(&s);
  return (float)h;
}
static __device__ inline short8v mk8(uint_t a, uint_t b, uint_t c, uint_t d) {
  union { int4 i; short8v s; } u;
  u.i = make_int4((int)a, (int)b, (int)c, (int)d);
  return u.s;
}
static __device__ inline float sum16(const f32x16 v) {
  float a = ((v[0] + v[1]) + (v[2] + v[3])) + ((v[4] + v[5]) + (v[6] + v[7]));
  float b = ((v[8] + v[9]) + (v[10] + v[11])) + ((v[12] + v[13]) + (v[14] + v[15]));
  return a + b;
}

// ---------------------------------------------------------------------------
// Kernel 1 (prep0): blocks [0,1024): sr_w -> Wf fragment layout.
// Blocks [1024,1040): WK2/WV2 (B-fragment-linear).  Block 1040: u, bp2.
__global__ __launch_bounds__(256) void prep0(
    const float* __restrict__ sr_w, const float* __restrict__ Wq,
    const float* __restrict__ Wkv, const float* __restrict__ bq,
    const float* __restrict__ Wp, const float* __restrict__ bkv,
    const float* __restrict__ bp, ushort_t* __restrict__ Wf,
    ushort_t* __restrict__ W2f, float* __restrict__ u,
    float* __restrict__ bp2) {
  const int bid = blockIdx.x;
  const int t = threadIdx.x;
  const float SC = 0.125f * 1.4426950408889634f;
  if (bid < 1024) {
    int idx = bid * 256 + t;      // 262144
    int o = idx >> 12;
    int r = idx & 4095;
    int c = r >> 6;
    int ki = (r >> 3) & 7;
    int kj = r & 7;
    int oh = o >> 5;
    int l = ((c >> 3) & 1) * 32 + (o & 31);
    int kk = kj * 4 + (c >> 4);
    int e = c & 7;
    Wf[(ki * 2 + oh) * 16384 + kk * 512 + l * 8 + e] = f2bf(sr_w[idx]);
  } else if (bid < 1040) {
    const int eb = bid - 1024;
#pragma unroll
    for (int q = 0; q < 2; ++q) {
      int oidx = eb * 512 + t * 2 + q;   // [0,8192)
      int mat = oidx >> 12;
      int rem = oidx & 4095;
      int d = rem >> 6;
      int c = rem & 63;
      float s = 0.f;
      if (mat == 0) {
        const float* wk = Wkv + d * 128;
        const float* wq = Wq + c * 64;
#pragma unroll 16
        for (int e = 0; e < 64; ++e) s += wk[e] * wq[e];
        s *= SC;
      } else {
        const float* wk = Wkv + d * 128 + 64;
#pragma unroll 16
        for (int e = 0; e < 64; ++e) s += wk[e] * Wp[e * 64 + c];
      }
      W2f[((mat * 2 + (c >> 5)) * 4 + (d >> 4)) * 512 +
          (((d >> 3) & 1) * 32 + (c & 31)) * 8 + (d & 7)] = f2bf(s);
    }
  } else {
    if (t < 64) {
      float s = 0.f;
      const float* wk = Wkv + t * 128;
#pragma unroll 16
      for (int e = 0; e < 64; ++e) s += wk[e] * bq[e];
      u[t] = s * SC;
    } else if (t < 128) {
      int c = t - 64;
      float s = bp[c];
#pragma unroll 16
      for (int e = 0; e < 64; ++e) s += bkv[64 + e] * Wp[e * 64 + c];
      bp2[c] = s;
    }
  }
}

// ---------------------------------------------------------------------------
// Kernel A: conv partial GEMM, K-split by kj-halves; fp16 partials (R18).
// Grid 1024 = half(2) x b(8) x pg(8) x ki(8). 128 thr = 2 waves (oh).
__global__ __launch_bounds__(128) void conv_mfma(
    const float* __restrict__ x, const ushort_t* __restrict__ Wf,
    ushort_t* __restrict__ parth) {
  const int t = threadIdx.x;
  const int bi = blockIdx.x;
  const int ki = bi & 7;
  const int pg = (bi >> 3) & 7;
  const int b = (bi >> 6) & 7;
  const int half = bi >> 9;
  const int oh = t >> 6;
  const int lane = t & 63;
  const int lo5 = lane & 31;
  const int hi = lane >> 5;

  const int P = pg * 32 + lo5;
  const int prow = P >> 4, pcol = P & 15;
  const float* rowbase =
      x + ((size_t)b * N + (prow * 8 + ki) * HW + pcol * 8) * C;
  const ushort_t* wbase = Wf + (ki * 2 + oh) * 16384 + lane * 8;

  f32x16 acc;
#pragma unroll
  for (int r = 0; r < 16; ++r) acc[r] = 0.f;

#pragma unroll
  for (int kkl = 0; kkl < 16; ++kkl) {
    const int kk = half * 16 + kkl;
    const int kj = kk >> 2;
    const int c0 = (kk & 3) * 16 + hi * 8;
    const float4* xp = reinterpret_cast<const float4*>(rowbase + kj * C + c0);
    float4 f0 = xp[0];
    float4 f1 = xp[1];
    short8v bfr = mk8(cvtpk(f0.x, f0.y), cvtpk(f0.z, f0.w), cvtpk(f1.x, f1.y),
                      cvtpk(f1.z, f1.w));
    short8v afr = *reinterpret_cast<const short8v*>(wbase + kk * 512);
    acc = __builtin_amdgcn_mfma_f32_32x32x16_bf16(afr, bfr, acc, 0, 0, 0);
  }

  // fp16 partials: 16 values -> 8 packed uints -> 2 coalesced 16B stores
  ushort_t* dst = parth + (size_t)bi * 2048 + oh * 1024 + lane * 16;
  uint4 v0 = make_uint4(pkh(acc[0], acc[1]), pkh(acc[2], acc[3]),
                        pkh(acc[4], acc[5]), pkh(acc[6], acc[7]));
  uint4 v1 = make_uint4(pkh(acc[8], acc[9]), pkh(acc[10], acc[11]),
                        pkh(acc[12], acc[13]), pkh(acc[14], acc[15]));
  *reinterpret_cast<uint4*>(dst) = v0;
  *reinterpret_cast<uint4*>(dst + 8) = v1;
}

// ---------------------------------------------------------------------------
// Kernel L: sum 16 K-split fp16 partials + bias + LayerNorm + MT/Vp/sb.
// Grid 64 = b(8) x pg(8).
__global__ __launch_bounds__(256) void ln_prep(
    const ushort_t* __restrict__ parth, const float* __restrict__ sr_b,
    const float* __restrict__ ln_g, const float* __restrict__ ln_b,
    const ushort_t* __restrict__ W2f, const float* __restrict__ u,
    ushort_t* __restrict__ MTf, ushort_t* __restrict__ VpTf,
    ushort_t* __restrict__ sbf) {
  __shared__ float convs[32 * 68];
  __shared__ float ns[32 * 68];

  const int t = threadIdx.x;
  const int b = blockIdx.x >> 3;
  const int pg = blockIdx.x & 7;
  const size_t obase = (size_t)b * 16384;

  // ---- Phase A: sum 16 (ki, half) fp16 partials + conv bias ----
  {
    const int lane = t & 63;
    const int rhalf = (t >> 6) & 1;
    const int oh = t >> 7;
    float a[8];
#pragma unroll
    for (int r = 0; r < 8; ++r) a[r] = 0.f;
#pragma unroll
    for (int k2 = 0; k2 < 16; ++k2) {
      int bi = (k2 & 7) + (pg << 3) + (b << 6) + ((k2 >> 3) << 9);
      const ushort_t* src =
          parth + (size_t)bi * 2048 + oh * 1024 + lane * 16 + rhalf * 8;
      uint4 uv = *reinterpret_cast<const uint4*>(src);
      a[0] += uf16lo(uv.x); a[1] += uf16hi(uv.x);
      a[2] += uf16lo(uv.y); a[3] += uf16hi(uv.y);
      a[4] += uf16lo(uv.z); a[5] += uf16hi(uv.z);
      a[6] += uf16lo(uv.w); a[7] += uf16hi(uv.w);
    }
    const int p = lane & 31;
#pragma unroll
    for (int r = 0; r < 8; ++r) {
      int reg = rhalf * 8 + r;
      int o = oh * 32 + (reg & 3) + 8 * (reg >> 2) + 4 * (lane >> 5);
      convs[p * 68 + o] = a[r] + sr_b[o];
    }
  }
  __syncthreads();
  // ---- Phase B: LayerNorm ----
  {
    const int lane = t & 63;
    const int w = t >> 6;
    float g = ln_g[lane], bb = ln_b[lane];
#pragma unroll
    for (int rr = 0; rr < 8; ++rr) {
      int p = w * 8 + rr;
      float v = convs[p * 68 + lane];
      float s = v, s2 = v * v;
#pragma unroll
      for (int mask = 1; mask < 64; mask <<= 1) {
        s += __shfl_xor(s, mask, 64);
        s2 += __shfl_xor(s2, mask, 64);
      }
      float mu = s * (1.f / 64.f);
      float var = s2 * (1.f / 64.f) - mu * mu;
      ns[p * 68 + lane] = (v - mu) * rsqrtf(var + 1e-5f) * g + bb;
    }
  }
  __syncthreads();
  // ---- Phase C: per-wave 32x32 GEMM tile (MT / Vp) + sb dot ----
  {
    const int w = t >> 6;
    const int lane = t & 63;
    const int lo5 = lane & 31;
    const int hi = lane >> 5;
    const int mat = w >> 1;
    const int n0 = w & 1;

    f32x16 acc;
#pragma unroll
    for (int r = 0; r < 16; ++r) acc[r] = 0.f;
#pragma unroll
    for (int ks = 0; ks < 4; ++ks) {
      float4 f0 = *reinterpret_cast<const float4*>(&ns[lo5 * 68 + ks * 16 + hi * 8]);
      float4 f1 = *reinterpret_cast<const float4*>(&ns[lo5 * 68 + ks * 16 + hi * 8 + 4]);
      short8v A = mk8(cvtpk(f0.x, f0.y), cvtpk(f0.z, f0.w), cvtpk(f1.x, f1.y),
                      cvtpk(f1.z, f1.w));
      short8v Bw = *reinterpret_cast<const short8v*>(
          W2f + ((mat * 2 + n0) * 4 + ks) * 512 + lane * 8);
      acc = __builtin_amdgcn_mfma_f32_32x32x16_bf16(A, Bw, acc, 0, 0, 0);
    }
    const int c = n0 * 32 + lo5;
    if (mat == 0) {
#pragma unroll
      for (int r = 0; r < 16; ++r) {
        int jl = (r & 3) + 8 * (r >> 2) + 4 * hi;
        MTf[obase + (pg * 4 + (c >> 4)) * 512 +
            (((c >> 3) & 1) * 32 + jl) * 8 + (c & 7)] = f2bf(acc[r]);
      }
    } else {
#pragma unroll
      for (int r = 0; r < 16; ++r) {
        int jg = pg * 32 + (r & 3) + 8 * (r >> 2) + 4 * hi;
        VpTf[obase + (n0 * 16 + (jg >> 4)) * 512 +
             (((jg >> 3) & 1) * 32 + (c & 31)) * 8 + (jg & 7)] = f2bf(acc[r]);
      }
    }
    if (w == 0) {
      float s = 0.f;
      const float* ub = u + hi * 32;
#pragma unroll 8
      for (int dd = 0; dd < 32; ++dd) s += ns[lo5 * 68 + hi * 32 + dd] * ub[dd];
      s += __shfl_xor(s, 32, 64);
      if (hi == 0) sbf[b * NK + pg * 32 + lo5] = f2bf(s);
    }
  }
}

// ---------------------------------------------------------------------------
// Kernel B (R24 = R19): fused attention, MT-only LDS, VpT global
// (L2-resident), coalesced LDS-staged epilogue, setprio (T5), manual 2-way
// kt interleave. Grid 1024 = b(8 hi) x qb(128); 256 thr = 4 waves;
// 4 blocks/CU = 16 waves/CU = 4 waves/SIMD.
__global__ __launch_bounds__(256, 4) void attn_mfma(
    const float* __restrict__ x, const ushort_t* __restrict__ MTf,
    const ushort_t* __restrict__ VpTf, const ushort_t* __restrict__ sbf,
    const float* __restrict__ bp2, float* __restrict__ outp) {
  // union region: sMT (32KB bf16 fragments) during the loop, then
  // sOut (4 waves x [32][68] fp32 = 34816B) for the coalesced epilogue.
  __shared__ __align__(16) char smem[34816 + 512];
  ushort_t* sMT = reinterpret_cast<ushort_t*>(smem);
  float* sOut = reinterpret_cast<float*>(smem);
  ushort_t* sSB = reinterpret_cast<ushort_t*>(smem + 34816);

  const int t = threadIdx.x;
  const int b = blockIdx.x >> 7;
  const int qb = blockIdx.x & 127;
  const int wave = t >> 6;
  const int lane = t & 63;
  const int lo5 = lane & 31;
  const int hi = lane >> 5;

  // ---- issue x loads FIRST (latency hides under staging + barrier) ----
  const int row = qb * 128 + wave * 32 + lo5;
  const float4* xp =
      reinterpret_cast<const float4*>(x + ((size_t)b * N + row) * 64);
  float4 xf[8];
#pragma unroll
  for (int ks = 0; ks < 4; ++ks) {
    xf[2 * ks + 0] = xp[ks * 4 + hi * 2 + 0];
    xf[2 * ks + 1] = xp[ks * 4 + hi * 2 + 1];
  }

  // ---- cooperative staging: MT + sb (256 threads, 32KB) ----
  {
    const uint4* gm = reinterpret_cast<const uint4*>(MTf + (size_t)b * 16384);
    uint4* dm = reinterpret_cast<uint4*>(sMT);
#pragma unroll
    for (int i = 0; i < 8; ++i) dm[t + i * 256] = gm[t + i * 256];
    if (t < 32)
      reinterpret_cast<uint4*>(sSB)[t] =
          reinterpret_cast<const uint4*>(sbf + b * NK)[t];
  }
  __syncthreads();

  // ---- pack X B-fragment (col=q=lane&31, k=c=ks*16+hi*8+e) ----
  short8v bx[4];
#pragma unroll
  for (int ks = 0; ks < 4; ++ks) {
    bx[ks] = mk8(cvtpk(xf[2 * ks].x, xf[2 * ks].y),
                 cvtpk(xf[2 * ks].z, xf[2 * ks].w),
                 cvtpk(xf[2 * ks + 1].x, xf[2 * ks + 1].y),
                 cvtpk(xf[2 * ks + 1].z, xf[2 * ks + 1].w));
  }

  const ushort_t* vt = VpTf + (size_t)b * 16384 + lane * 8;

  f32x16 zv;
#pragma unroll
  for (int r = 0; r < 16; ++r) zv[r] = 0.f;

  f32x16 o[2];
#pragma unroll
  for (int ct = 0; ct < 2; ++ct)
#pragma unroll
    for (int r = 0; r < 16; ++r) o[ct][r] = 0.f;
  float sum = 0.f;

#pragma unroll 1
  for (int kt2 = 0; kt2 < 4; ++kt2) {
    const int kta = kt2 * 2;
    const int ktb = kta + 1;
    // ---- QK^T: two independent chains (a0 for kta, a1 for ktb) ----
    __builtin_amdgcn_s_setprio(1);
    const short8v afa0 =
        *reinterpret_cast<const short8v*>(&sMT[(kta * 4 + 0) * 512 + lane * 8]);
    const short8v afb0 =
        *reinterpret_cast<const short8v*>(&sMT[(ktb * 4 + 0) * 512 + lane * 8]);
    f32x16 a0 = __builtin_amdgcn_mfma_f32_32x32x16_bf16(afa0, bx[0], zv, 0, 0, 0);
    f32x16 a1 = __builtin_amdgcn_mfma_f32_32x32x16_bf16(afb0, bx[0], zv, 0, 0, 0);
#pragma unroll
    for (int ks = 1; ks < 4; ++ks) {
      const short8v aa =
          *reinterpret_cast<const short8v*>(&sMT[(kta * 4 + ks) * 512 + lane * 8]);
      const short8v ab =
          *reinterpret_cast<const short8v*>(&sMT[(ktb * 4 + ks) * 512 + lane * 8]);
      a0 = __builtin_amdgcn_mfma_f32_32x32x16_bf16(aa, bx[ks], a0, 0, 0, 0);
      a1 = __builtin_amdgcn_mfma_f32_32x32x16_bf16(ab, bx[ks], a1, 0, 0, 0);
    }
    // bias k-step for both tiles
    {
      ushort_t sva = sSB[kta * 32 + lo5];
      ushort_t svb = sSB[ktb * 32 + lo5];
      short8v b5 = mk8(hi ? 0u : 0x3F80u, 0u, 0u, 0u);
      short8v a5a = mk8(hi ? 0u : (uint_t)sva, 0u, 0u, 0u);
      short8v a5b = mk8(hi ? 0u : (uint_t)svb, 0u, 0u, 0u);
      a0 = __builtin_amdgcn_mfma_f32_32x32x16_bf16(a5a, b5, a0, 0, 0, 0);
      a1 = __builtin_amdgcn_mfma_f32_32x32x16_bf16(a5b, b5, a1, 0, 0, 0);
    }
    __builtin_amdgcn_s_setprio(0);
    // ---- exp2 both chains (independent trans-unit streams) ----
#pragma unroll
    for (int r = 0; r < 16; ++r) a0[r] = __builtin_amdgcn_exp2f(a0[r]);
#pragma unroll
    for (int r = 0; r < 16; ++r) a1[r] = __builtin_amdgcn_exp2f(a1[r]);
    sum += sum16(a0) + sum16(a1);
    // ---- pack P + PV: 4 phases (kta.h0, kta.h1, ktb.h0, ktb.h1) ----
#pragma unroll
    for (int ph = 0; ph < 4; ++ph) {
      const int kt = (ph < 2) ? kta : ktb;
      const int m0 = (ph & 1) * 2;
      const f32x16& av = (ph < 2) ? a0 : a1;
      uint_t Aw = cvtpk(av[4 * m0 + 0], av[4 * m0 + 1]);
      uint_t Bw = cvtpk(av[4 * m0 + 2], av[4 * m0 + 3]);
      uint_t Cw = cvtpk(av[4 * m0 + 4], av[4 * m0 + 5]);
      uint_t Dw = cvtpk(av[4 * m0 + 6], av[4 * m0 + 7]);
      asm volatile("v_permlane32_swap_b32 %0, %1" : "+v"(Aw), "+v"(Cw));
      asm volatile("v_permlane32_swap_b32 %0, %1" : "+v"(Bw), "+v"(Dw));
      const short8v pb = mk8(Aw, Bw, Cw, Dw);
      const int kss = kt * 2 + (ph & 1);
      __builtin_amdgcn_s_setprio(1);
#pragma unroll
      for (int ct = 0; ct < 2; ++ct) {
        const short8v va =
            *reinterpret_cast<const short8v*>(vt + (ct * 16 + kss) * 512);
        o[ct] = __builtin_amdgcn_mfma_f32_32x32x16_bf16(va, pb, o[ct], 0, 0, 0);
      }
      __builtin_amdgcn_s_setprio(0);
    }
  }

  sum += __shfl_xor(sum, 32, 64);
  const float linv = 1.f / sum;

  // ---- epilogue: stage (o*linv + bp2) into LDS, then coalesced stores ----
  __syncthreads();   // all waves done reading sMT; region becomes sOut
  {
    float* wout = sOut + wave * 2176;   // [32][68] fp32 per wave
#pragma unroll
    for (int ct = 0; ct < 2; ++ct) {
#pragma unroll
      for (int g = 0; g < 4; ++g) {
        int c0 = ct * 32 + g * 8 + hi * 4;
        float4 bpv = *reinterpret_cast<const float4*>(bp2 + c0);
        float4 r;
        r.x = o[ct][4 * g + 0] * linv + bpv.x;
        r.y = o[ct][4 * g + 1] * linv + bpv.y;
        r.z = o[ct][4 * g + 2] * linv + bpv.z;
        r.w = o[ct][4 * g + 3] * linv + bpv.w;
        *reinterpret_cast<float4*>(&wout[lo5 * 68 + c0]) = r;
      }
    }
  }
  __syncthreads();
  {
    float* outBase = outp + (((size_t)b * N + qb * 128) * 64);
#pragma unroll
    for (int qi = 0; qi < 8; ++qi) {
      int rowl = qi * 16 + (t >> 4);          // block-local query row
      int c4 = (t & 15) * 4;                  // channel quad
      float4 v = *reinterpret_cast<const float4*>(
          &sOut[(rowl >> 5) * 2176 + (rowl & 31) * 68 + c4]);
      // linear float idx qi*1024 + t*4: consecutive lanes -> contiguous 16B
      *reinterpret_cast<float4*>(outBase + qi * 1024 + t * 4) = v;
    }
  }
}

// ---------------------------------------------------------------------------
extern "C" void kernel_launch(void* const* d_in, const int* in_sizes, int n_in,
                              void* d_out, int out_size, void* d_ws,
                              size_t ws_size, hipStream_t stream) {
  const float* x    = (const float*)d_in[0];
  const float* Wq   = (const float*)d_in[3];
  const float* bq   = (const float*)d_in[4];
  const float* Wkv  = (const float*)d_in[5];
  const float* bkv  = (const float*)d_in[6];
  const float* sr_w = (const float*)d_in[7];
  const float* sr_b = (const float*)d_in[8];
  const float* ln_g = (const float*)d_in[9];
  const float* ln_b = (const float*)d_in[10];
  const float* Wp   = (const float*)d_in[11];
  const float* bp   = (const float*)d_in[12];
  float* outp = (float*)d_out;

  char* ws = (char*)d_ws;
  // [0, 512K)      Wf    bf16 conv weight fragments
  // [512K, 528K)   W2f   bf16 WK2/WV2 fragments
  // [528K, +256)   u     fp32[64];  [+256, +512) bp2 fp32[64]
  // [1M, 5M)       parth fp16 conv partials (1024 units x 4KB)
  // [9M, 9.25M)    MTf   [9.25M, 9.5M) VpTf   [9.5M, +4K) sbf
  ushort_t* Wf    = (ushort_t*)(ws);
  ushort_t* W2f   = (ushort_t*)(ws + (512 << 10));
  float*    u     = (float*)(ws + (528 << 10));
  float*    bp2   = (float*)(ws + (528 << 10) + 256);
  ushort_t* parth = (ushort_t*)(ws + (1024 << 10));
  ushort_t* MTf   = (ushort_t*)(ws + (9216 << 10));
  ushort_t* VpTf  = (ushort_t*)(ws + (9472 << 10));
  ushort_t* sbf   = (ushort_t*)(ws + (9728 << 10));

  prep0<<<1041, 256, 0, stream>>>(sr_w, Wq, Wkv, bq, Wp, bkv, bp, Wf, W2f, u, bp2);
  conv_mfma<<<1024, 128, 0, stream>>>(x, Wf, parth);
  ln_prep<<<64, 256, 0, stream>>>(parth, sr_b, ln_g, ln_b, W2f, u, MTf, VpTf, sbf);
  attn_mfma<<<1024, 256, 0, stream>>>(x, MTf, VpTf, sbf, bp2, outp);
}